// Round 2
// baseline (839.400 us; speedup 1.0000x reference)
//
#include <hip/hip_runtime.h>
#include <math.h>

#define N      6144
#define NVIEW  3
#define NFEAT  512
#define K      10
#define BN_EPS 1e-5f

#define MC      1024     // z-tile rows per LDS chunk
#define ROWS_PB 24       // rows per block
#define RPW     6        // rows per wave

// ---------- device helpers ----------
__device__ __forceinline__ float softplus1(float x) {
    // jax.nn.softplus(x) + 1 = logaddexp(x,0) + 1
    return fmaxf(x, 0.f) + log1pf(expf(-fabsf(x))) + 1.f;
}

__device__ __forceinline__ float selu_f(float x) {
    const float al = 1.6732632423543772f, sc = 1.0507009873554805f;
    return x > 0.f ? sc * x : sc * al * expm1f(x);
}

// Dempster–Shafer combination of two Dirichlet evidences (K classes)
__device__ __forceinline__ void ds_comb(const float* a1, const float* a2, float* o) {
    float S1 = 0.f, S2 = 0.f;
#pragma unroll
    for (int k = 0; k < K; ++k) { S1 += a1[k]; S2 += a2[k]; }
    const float r1 = 1.f / S1, r2 = 1.f / S2;
    float b1[K], b2[K];
    float sb1 = 0.f, sb2 = 0.f, dot = 0.f;
#pragma unroll
    for (int k = 0; k < K; ++k) {
        b1[k] = (a1[k] - 1.f) * r1;
        b2[k] = (a2[k] - 1.f) * r2;
        sb1 += b1[k]; sb2 += b2[k]; dot += b1[k] * b2[k];
    }
    const float u1 = (float)K * r1, u2 = (float)K * r2;
    const float C   = sb1 * sb2 - dot;
    const float inv = 1.f / (1.f - C);
    const float u   = u1 * u2 * inv;
    const float S   = (float)K / u;
#pragma unroll
    for (int k = 0; k < K; ++k)
        o[k] = (b1[k] * b2[k] + b1[k] * u2 + b2[k] * u1) * inv * S + 1.f;
}

// FMA a float4 lap vector against 10 zk float4 columns
#define FMA4(lvv)                                                   \
    do {                                                            \
        _Pragma("unroll")                                           \
        for (int k = 0; k < K; ++k) {                               \
            acc[r][k] = fmaf((lvv).x, zk[k].x, acc[r][k]);          \
            acc[r][k] = fmaf((lvv).y, zk[k].y, acc[r][k]);          \
            acc[r][k] = fmaf((lvv).z, zk[k].z, acc[r][k]);          \
            acc[r][k] = fmaf((lvv).w, zk[k].w, acc[r][k]);          \
        }                                                           \
    } while (0)

// ---------- proj = einsum('vnf,vfk->vnk', features, U) ----------
__global__ __launch_bounds__(256, 4)
void proj_kernel(const float* __restrict__ feat, const float* __restrict__ U,
                 float* __restrict__ proj) {
    // U transposed in LDS: uT[k][f], word stride NFEAT+4 (rows 16B aligned,
    // float4 reads at 4*lane spread over 8 bank groups ~= 2.9x, acceptable)
    __shared__ float uT[K][NFEAT + 4];
    const int tid  = threadIdx.x;
    const int lane = tid & 63;
    const int wid  = tid >> 6;                 // 0..3
    const int v    = blockIdx.x / (N / ROWS_PB);
    const int nb   = blockIdx.x % (N / ROWS_PB);
    const int row0 = nb * ROWS_PB + wid * RPW;

    for (int f = tid; f < NFEAT * K; f += 256)
        uT[f % K][f / K] = U[(size_t)v * NFEAT * K + f];
    __syncthreads();

    const float* fr[RPW];
#pragma unroll
    for (int r = 0; r < RPW; ++r)
        fr[r] = feat + ((size_t)v * N + (row0 + r)) * (size_t)NFEAT;

    float acc[RPW][K];
#pragma unroll
    for (int r = 0; r < RPW; ++r)
#pragma unroll
        for (int k = 0; k < K; ++k) acc[r][k] = 0.f;

#pragma unroll
    for (int s = 0; s < NFEAT / 256; ++s) {
        const int mloc = s * 256 + lane * 4;
        float4 lv[RPW];
#pragma unroll
        for (int r = 0; r < RPW; ++r)
            lv[r] = *reinterpret_cast<const float4*>(fr[r] + mloc);
        float4 zk[K];
#pragma unroll
        for (int k = 0; k < K; ++k)
            zk[k] = *reinterpret_cast<const float4*>(&uT[k][mloc]);
#pragma unroll
        for (int r = 0; r < RPW; ++r) FMA4(lv[r]);
    }
#pragma unroll
    for (int r = 0; r < RPW; ++r)
#pragma unroll
        for (int k = 0; k < K; ++k) {
            float x = acc[r][k];
#pragma unroll
            for (int off = 32; off > 0; off >>= 1) x += __shfl_xor(x, off);
            acc[r][k] = x;
        }
    if (lane == 0) {
#pragma unroll
        for (int r = 0; r < RPW; ++r)
#pragma unroll
            for (int k = 0; k < K; ++k)
                proj[((size_t)v * N + (row0 + r)) * K + k] = acc[r][k];
    }
}

// ---------- evid: S_v = lap_v @ z ; H_v = z - S_v + proj_v ; DS-combine ----------
__global__ __launch_bounds__(768, 1)
void evid_kernel(const float* __restrict__ lap, const float* __restrict__ zsrc,
                 const float* __restrict__ proj, float* __restrict__ h_out,
                 float* __restrict__ partials) {
    // z transposed in LDS: zT[k][m], word stride MC+4 = 1028 (rows 16B aligned)
    __shared__ float zT[K][MC + 4];
    __shared__ float S_lds[NVIEW][ROWS_PB][K];
    __shared__ float h_lds[ROWS_PB][K];

    const int tid  = threadIdx.x;
    const int lane = tid & 63;
    const int wid  = tid >> 6;       // 0..11
    const int v    = wid >> 2;       // view 0..2
    const int rg   = wid & 3;        // rowgroup 0..3
    const int row0 = blockIdx.x * ROWS_PB + rg * RPW;

    const float* lapr[RPW];
#pragma unroll
    for (int r = 0; r < RPW; ++r)
        lapr[r] = lap + ((size_t)v * N + (row0 + r)) * (size_t)N;

    float acc[RPW][K];
#pragma unroll
    for (int r = 0; r < RPW; ++r)
#pragma unroll
        for (int k = 0; k < K; ++k) acc[r][k] = 0.f;

    for (int mc = 0; mc < N; mc += MC) {
        // stage z chunk transposed (coalesced global read)
        for (int f = tid; f < MC * K; f += 768)
            zT[f % K][f / K] = zsrc[(size_t)mc * K + f];
        __syncthreads();
#pragma unroll
        for (int s = 0; s < MC / 256; ++s) {
            const int mloc = s * 256 + lane * 4;
            float4 lv[RPW];
#pragma unroll
            for (int r = 0; r < RPW; ++r)
                lv[r] = *reinterpret_cast<const float4*>(lapr[r] + mc + mloc);
            float4 zk[K];
#pragma unroll
            for (int k = 0; k < K; ++k)
                zk[k] = *reinterpret_cast<const float4*>(&zT[k][mloc]);
#pragma unroll
            for (int r = 0; r < RPW; ++r) FMA4(lv[r]);
        }
        __syncthreads();
    }

    // cross-lane reduction of the dot products
#pragma unroll
    for (int r = 0; r < RPW; ++r)
#pragma unroll
        for (int k = 0; k < K; ++k) {
            float x = acc[r][k];
#pragma unroll
            for (int off = 32; off > 0; off >>= 1) x += __shfl_xor(x, off);
            acc[r][k] = x;
        }
    if (lane == 0) {
#pragma unroll
        for (int r = 0; r < RPW; ++r)
#pragma unroll
            for (int k = 0; k < K; ++k)
                S_lds[v][rg * RPW + r][k] = acc[r][k];
    }
    __syncthreads();

    // epilogue: evidences + DS combine (one thread per row)
    if (tid < ROWS_PB) {
        const int n = blockIdx.x * ROWS_PB + tid;
        float a[NVIEW][K];
#pragma unroll
        for (int vv = 0; vv < NVIEW; ++vv)
#pragma unroll
            for (int k = 0; k < K; ++k) {
                const float H = zsrc[(size_t)n * K + k] - S_lds[vv][tid][k]
                              + proj[((size_t)vv * N + n) * K + k];
                a[vv][k] = softplus1(H);
            }
        float c1[K], c2[K];
        ds_comb(a[0], a[1], c1);
        ds_comb(c1, a[2], c2);
#pragma unroll
        for (int k = 0; k < K; ++k) {
            h_out[(size_t)n * K + k] = c2[k];
            h_lds[tid][k] = c2[k];
        }
    }
    __syncthreads();

    // per-block BN partial sums
    if (tid < K) {
        float s = 0.f, s2 = 0.f;
#pragma unroll
        for (int i = 0; i < ROWS_PB; ++i) {
            const float x = h_lds[i][tid];
            s += x; s2 += x * x;
        }
        partials[blockIdx.x * 2 * K + tid]     = s;
        partials[blockIdx.x * 2 * K + K + tid] = s2;
    }
}

// ---------- finalize: BN (batch stats) + SELU soft-threshold ----------
__global__ __launch_bounds__(256)
void finalize_kernel(const float* __restrict__ h, const float* __restrict__ partials,
                     const float* __restrict__ gamma, const float* __restrict__ beta,
                     const float* __restrict__ theta, float* __restrict__ z_out,
                     float* __restrict__ out) {
    __shared__ float wsum[4][2 * K];
    __shared__ float mu_s[K], sc_s[K], beta_s[K];
    const int tid  = threadIdx.x;
    const int lane = tid & 63;
    const int wid  = tid >> 6;

    float p[2 * K];
#pragma unroll
    for (int j = 0; j < 2 * K; ++j) p[j] = partials[tid * 2 * K + j];
#pragma unroll
    for (int j = 0; j < 2 * K; ++j) {
        float x = p[j];
#pragma unroll
        for (int off = 32; off > 0; off >>= 1) x += __shfl_xor(x, off);
        p[j] = x;
    }
    if (lane == 0) {
#pragma unroll
        for (int j = 0; j < 2 * K; ++j) wsum[wid][j] = p[j];
    }
    __syncthreads();
    if (tid < K) {
        const float s  = wsum[0][tid] + wsum[1][tid] + wsum[2][tid] + wsum[3][tid];
        const float s2 = wsum[0][K+tid] + wsum[1][K+tid] + wsum[2][K+tid] + wsum[3][K+tid];
        const float mu  = s / (float)N;
        const float var = s2 / (float)N - mu * mu;
        mu_s[tid]   = mu;
        sc_s[tid]   = gamma[tid] / sqrtf(var + BN_EPS);
        beta_s[tid] = beta[tid];
    }
    __syncthreads();

    const float th = theta[0];
    const int   n  = blockIdx.x * 256 + tid;
    const float2* hp = reinterpret_cast<const float2*>(h + (size_t)n * K);
    float hv[K];
#pragma unroll
    for (int j = 0; j < 5; ++j) {
        const float2 t = hp[j];
        hv[2 * j]     = t.x;
        hv[2 * j + 1] = t.y;
    }
    float zv[K];
#pragma unroll
    for (int k = 0; k < K; ++k) {
        const float hn = (hv[k] - mu_s[k]) * sc_s[k] + beta_s[k];
        zv[k] = selu_f(hn - th) - selu_f(-hn - th);
    }
    float2* zo = reinterpret_cast<float2*>(z_out + (size_t)n * K);
    float2* oo = reinterpret_cast<float2*>(out + (size_t)n * K);
#pragma unroll
    for (int j = 0; j < 5; ++j) {
        float2 t;
        t.x = zv[2 * j]; t.y = zv[2 * j + 1];
        zo[j] = t;
        oo[j] = t;
    }
}

// ---------- host ----------
extern "C" void kernel_launch(void* const* d_in, const int* in_sizes, int n_in,
                              void* d_out, int out_size, void* d_ws, size_t ws_size,
                              hipStream_t stream) {
    const float* features = (const float*)d_in[0];
    const float* lap      = (const float*)d_in[1];
    const float* z_init   = (const float*)d_in[2];
    const float* U        = (const float*)d_in[3];
    const float* theta    = (const float*)d_in[4];
    const float* gamma    = (const float*)d_in[5];
    const float* beta     = (const float*)d_in[6];
    float* out = (float*)d_out;

    float* ws       = (float*)d_ws;
    float* proj     = ws;                                   // V*N*K
    float* h_buf    = proj + (size_t)NVIEW * N * K;         // N*K
    float* z_buf    = h_buf + (size_t)N * K;                // N*K
    float* partials = z_buf + (size_t)N * K;                // 256*2*K

    proj_kernel<<<NVIEW * (N / ROWS_PB), 256, 0, stream>>>(features, U, proj);

    // iteration 0 (z = z_init)
    evid_kernel<<<N / ROWS_PB, 768, 0, stream>>>(lap, z_init, proj, h_buf, partials);
    finalize_kernel<<<N / 256, 256, 0, stream>>>(h_buf, partials, gamma, beta, theta,
                                                 z_buf, out);
    // iteration 1 (z = z_buf)
    evid_kernel<<<N / ROWS_PB, 768, 0, stream>>>(lap, z_buf, proj, h_buf, partials);
    finalize_kernel<<<N / 256, 256, 0, stream>>>(h_buf, partials, gamma, beta, theta,
                                                 z_buf, out + (size_t)N * K);
}